// Round 1
// baseline (148.019 us; speedup 1.0000x reference)
//
#include <hip/hip_runtime.h>
#include <math.h>

namespace {

constexpr int KC  = 5;
constexpr int DIM = 1088;
constexpr int D4  = DIM / 4;        // 272 float4 per row
constexpr int FULL_IT = D4 / 64;    // 4 full wave-iterations
constexpr int REM     = D4 % 64;    // 16 leftover float4 (lanes 0..15)

__global__ void zero_out_kernel(float* out) { out[0] = 0.0f; }

__global__ __launch_bounds__(256) void mdn_loss_kernel(
    const float* __restrict__ target,
    const float* __restrict__ s_mean,
    const float* __restrict__ s_logstd,
    const float* __restrict__ log_mix,
    float* __restrict__ out,
    int n_rows, float inv_n)
{
    const int wave_in_block = threadIdx.x >> 6;
    const int lane          = threadIdx.x & 63;
    const int row           = blockIdx.x * (blockDim.x >> 6) + wave_in_block;

    float row_loss = 0.0f;

    if (row < n_rows) {
        const float4* tg = reinterpret_cast<const float4*>(target) + (size_t)row * D4;

        // Cache target row in registers (read once, reused for all K components).
        float4 t[FULL_IT + 1];
        #pragma unroll
        for (int i = 0; i < FULL_IT; ++i) t[i] = tg[lane + i * 64];
        if (lane < REM) t[FULL_IT] = tg[lane + FULL_IT * 64];

        const float4* mrow = reinterpret_cast<const float4*>(s_mean)   + (size_t)row * (KC * D4);
        const float4* lrow = reinterpret_cast<const float4*>(s_logstd) + (size_t)row * (KC * D4);

        float a[KC];
        #pragma unroll
        for (int k = 0; k < KC; ++k) {
            const float4* mk = mrow + k * D4;
            const float4* lk = lrow + k * D4;
            float z2 = 0.0f, lsum = 0.0f;
            #pragma unroll
            for (int i = 0; i < FULL_IT; ++i) {
                const float4 m4 = mk[lane + i * 64];
                const float4 l4 = lk[lane + i * 64];
                const float4 t4 = t[i];
                float r;
                r = (t4.x - m4.x) * __expf(-l4.x); z2 = fmaf(r, r, z2); lsum += l4.x;
                r = (t4.y - m4.y) * __expf(-l4.y); z2 = fmaf(r, r, z2); lsum += l4.y;
                r = (t4.z - m4.z) * __expf(-l4.z); z2 = fmaf(r, r, z2); lsum += l4.z;
                r = (t4.w - m4.w) * __expf(-l4.w); z2 = fmaf(r, r, z2); lsum += l4.w;
            }
            if (lane < REM) {
                const float4 m4 = mk[lane + FULL_IT * 64];
                const float4 l4 = lk[lane + FULL_IT * 64];
                const float4 t4 = t[FULL_IT];
                float r;
                r = (t4.x - m4.x) * __expf(-l4.x); z2 = fmaf(r, r, z2); lsum += l4.x;
                r = (t4.y - m4.y) * __expf(-l4.y); z2 = fmaf(r, r, z2); lsum += l4.y;
                r = (t4.z - m4.z) * __expf(-l4.z); z2 = fmaf(r, r, z2); lsum += l4.z;
                r = (t4.w - m4.w) * __expf(-l4.w); z2 = fmaf(r, r, z2); lsum += l4.w;
            }
            // 64-lane butterfly reduction
            #pragma unroll
            for (int off = 32; off; off >>= 1) {
                z2   += __shfl_xor(z2, off);
                lsum += __shfl_xor(lsum, off);
            }
            a[k] = -0.5f * z2 - lsum;
        }

        if (lane == 0) {
            const float* lm = log_mix + (size_t)row * KC;
            float mx = -INFINITY;
            #pragma unroll
            for (int k = 0; k < KC; ++k) { a[k] += lm[k]; mx = fmaxf(mx, a[k]); }
            float s = 0.0f;
            #pragma unroll
            for (int k = 0; k < KC; ++k) s += __expf(a[k] - mx);
            row_loss = -(mx + __logf(s)) * inv_n;   // negative logsumexp, pre-scaled by 1/N
        }
    }

    // Block-level combine: 4 waves -> 1 atomicAdd per block (4096 total).
    __shared__ float part[4];
    if (lane == 0) part[wave_in_block] = row_loss;
    __syncthreads();
    if (threadIdx.x == 0) {
        atomicAdd(out, part[0] + part[1] + part[2] + part[3]);
    }
}

} // anonymous namespace

extern "C" void kernel_launch(void* const* d_in, const int* in_sizes, int n_in,
                              void* d_out, int out_size, void* d_ws, size_t ws_size,
                              hipStream_t stream)
{
    const float* target   = (const float*)d_in[0];
    const float* s_mean   = (const float*)d_in[1];
    const float* s_logstd = (const float*)d_in[2];
    const float* log_mix  = (const float*)d_in[3];
    float* out = (float*)d_out;

    const int n_rows = in_sizes[0] / DIM;   // 16384

    // Output accumulator must be zeroed every call (graph replays don't re-poison).
    zero_out_kernel<<<1, 1, 0, stream>>>(out);

    const int waves_per_block = 4;          // 256 threads
    const int blocks = (n_rows + waves_per_block - 1) / waves_per_block;
    mdn_loss_kernel<<<blocks, 256, 0, stream>>>(target, s_mean, s_logstd, log_mix,
                                                out, n_rows, 1.0f / n_rows);
}

// Round 2
// 132.377 us; speedup vs baseline: 1.1182x; 1.1182x over previous
//
#include <hip/hip_runtime.h>
#include <math.h>

namespace {

typedef float f32x4 __attribute__((ext_vector_type(4)));

constexpr int KC  = 5;
constexpr int DIM = 1088;
constexpr int D4  = DIM / 4;        // 272 float4 per row
constexpr int FULL_IT = D4 / 64;    // 4 full wave-iterations
constexpr int REM     = D4 % 64;    // 16 leftover float4 (lanes 0..15)

__global__ void zero_out_kernel(float* out) { out[0] = 0.0f; }

__global__ __launch_bounds__(512) void mdn_loss_kernel(
    const float* __restrict__ target,
    const float* __restrict__ s_mean,
    const float* __restrict__ s_logstd,
    const float* __restrict__ log_mix,
    float* __restrict__ out,
    int n_rows, float inv_n)
{
    const int wave_in_block = threadIdx.x >> 6;
    const int lane          = threadIdx.x & 63;
    const int row           = blockIdx.x * (blockDim.x >> 6) + wave_in_block;

    float row_loss = 0.0f;

    if (row < n_rows) {
        const f32x4* tg = reinterpret_cast<const f32x4*>(target) + (size_t)row * D4;

        // Cache target row in registers (read once, reused for all K components).
        f32x4 t[FULL_IT + 1];
        #pragma unroll
        for (int i = 0; i < FULL_IT; ++i)
            t[i] = __builtin_nontemporal_load(tg + lane + i * 64);
        if (lane < REM)
            t[FULL_IT] = __builtin_nontemporal_load(tg + lane + FULL_IT * 64);

        const f32x4* mrow = reinterpret_cast<const f32x4*>(s_mean)   + (size_t)row * (KC * D4);
        const f32x4* lrow = reinterpret_cast<const f32x4*>(s_logstd) + (size_t)row * (KC * D4);

        float a[KC];
        #pragma unroll 1   // keep k rolled: bounds VGPRs, 10 loads in flight per iter
        for (int k = 0; k < KC; ++k) {
            const f32x4* mk = mrow + k * D4;
            const f32x4* lk = lrow + k * D4;

            // Issue ALL loads for this component before any compute.
            f32x4 m[FULL_IT + 1], l[FULL_IT + 1];
            #pragma unroll
            for (int i = 0; i < FULL_IT; ++i) {
                m[i] = __builtin_nontemporal_load(mk + lane + i * 64);
                l[i] = __builtin_nontemporal_load(lk + lane + i * 64);
            }
            if (lane < REM) {
                m[FULL_IT] = __builtin_nontemporal_load(mk + lane + FULL_IT * 64);
                l[FULL_IT] = __builtin_nontemporal_load(lk + lane + FULL_IT * 64);
            }

            // Dual accumulators break the serial fma chain.
            float z2a = 0.0f, z2b = 0.0f, lsa = 0.0f, lsb = 0.0f;
            #pragma unroll
            for (int i = 0; i < FULL_IT; ++i) {
                float r0 = (t[i].x - m[i].x) * __expf(-l[i].x);
                float r1 = (t[i].y - m[i].y) * __expf(-l[i].y);
                float r2 = (t[i].z - m[i].z) * __expf(-l[i].z);
                float r3 = (t[i].w - m[i].w) * __expf(-l[i].w);
                z2a = fmaf(r0, r0, z2a);  lsa += l[i].x;
                z2b = fmaf(r1, r1, z2b);  lsb += l[i].y;
                z2a = fmaf(r2, r2, z2a);  lsa += l[i].z;
                z2b = fmaf(r3, r3, z2b);  lsb += l[i].w;
            }
            if (lane < REM) {
                float r0 = (t[FULL_IT].x - m[FULL_IT].x) * __expf(-l[FULL_IT].x);
                float r1 = (t[FULL_IT].y - m[FULL_IT].y) * __expf(-l[FULL_IT].y);
                float r2 = (t[FULL_IT].z - m[FULL_IT].z) * __expf(-l[FULL_IT].z);
                float r3 = (t[FULL_IT].w - m[FULL_IT].w) * __expf(-l[FULL_IT].w);
                z2a = fmaf(r0, r0, z2a);  lsa += l[FULL_IT].x;
                z2b = fmaf(r1, r1, z2b);  lsb += l[FULL_IT].y;
                z2a = fmaf(r2, r2, z2a);  lsa += l[FULL_IT].z;
                z2b = fmaf(r3, r3, z2b);  lsb += l[FULL_IT].w;
            }
            float z2 = z2a + z2b, lsum = lsa + lsb;

            // 64-lane butterfly reduction
            #pragma unroll
            for (int off = 32; off; off >>= 1) {
                z2   += __shfl_xor(z2, off);
                lsum += __shfl_xor(lsum, off);
            }
            a[k] = -0.5f * z2 - lsum;
        }

        if (lane == 0) {
            const float* lm = log_mix + (size_t)row * KC;
            float mx = -INFINITY;
            #pragma unroll
            for (int k = 0; k < KC; ++k) { a[k] += lm[k]; mx = fmaxf(mx, a[k]); }
            float s = 0.0f;
            #pragma unroll
            for (int k = 0; k < KC; ++k) s += __expf(a[k] - mx);
            row_loss = -(mx + __logf(s)) * inv_n;   // negative logsumexp, pre-scaled by 1/N
        }
    }

    // Block-level combine: 8 waves -> 1 atomicAdd per block (2048 total).
    __shared__ float part[8];
    if (lane == 0) part[wave_in_block] = row_loss;
    __syncthreads();
    if (threadIdx.x == 0) {
        float s = 0.0f;
        #pragma unroll
        for (int w = 0; w < 8; ++w) s += part[w];
        atomicAdd(out, s);
    }
}

} // anonymous namespace

extern "C" void kernel_launch(void* const* d_in, const int* in_sizes, int n_in,
                              void* d_out, int out_size, void* d_ws, size_t ws_size,
                              hipStream_t stream)
{
    const float* target   = (const float*)d_in[0];
    const float* s_mean   = (const float*)d_in[1];
    const float* s_logstd = (const float*)d_in[2];
    const float* log_mix  = (const float*)d_in[3];
    float* out = (float*)d_out;

    const int n_rows = in_sizes[0] / DIM;   // 16384

    // Output accumulator must be zeroed every call (graph replays don't re-poison).
    zero_out_kernel<<<1, 1, 0, stream>>>(out);

    const int waves_per_block = 8;          // 512 threads
    const int blocks = (n_rows + waves_per_block - 1) / waves_per_block;
    mdn_loss_kernel<<<blocks, 512, 0, stream>>>(target, s_mean, s_logstd, log_mix,
                                                out, n_rows, 1.0f / n_rows);
}

// Round 3
// 123.208 us; speedup vs baseline: 1.2014x; 1.0744x over previous
//
#include <hip/hip_runtime.h>
#include <math.h>

namespace {

typedef float f32x4 __attribute__((ext_vector_type(4)));

constexpr int KC  = 5;
constexpr int DIM = 1088;
constexpr int D4  = DIM / 4;        // 272 float4 per row
constexpr int FULL_IT = D4 / 64;    // 4 full wave-iterations
constexpr int REM     = D4 % 64;    // 16 leftover float4 (lanes 0..15)
constexpr int WPB     = 8;          // waves per block (512 threads)

__global__ void zero_out_kernel(float* out) { out[0] = 0.0f; }

__global__ __launch_bounds__(512) void mdn_loss_kernel(
    const float* __restrict__ target,
    const float* __restrict__ s_mean,
    const float* __restrict__ s_logstd,
    const float* __restrict__ log_mix,
    float* __restrict__ out,
    float* __restrict__ partials,   // may be null -> atomic path
    int n_rows, float inv_n, int use_partials)
{
    const int wave_in_block = threadIdx.x >> 6;
    const int lane          = threadIdx.x & 63;
    const int row           = blockIdx.x * WPB + wave_in_block;

    float row_loss = 0.0f;

    if (row < n_rows) {
        // Hoist log-mix coefficients: issued early, in flight during streaming.
        const float* lmp = log_mix + (size_t)row * KC;
        float lm[KC];
        #pragma unroll
        for (int k = 0; k < KC; ++k) lm[k] = lmp[k];

        const f32x4* tg = reinterpret_cast<const f32x4*>(target) + (size_t)row * D4;

        // Cache target row in registers (read once, reused for all K components).
        f32x4 t[FULL_IT + 1];
        #pragma unroll
        for (int i = 0; i < FULL_IT; ++i)
            t[i] = __builtin_nontemporal_load(tg + lane + i * 64);
        if (lane < REM)
            t[FULL_IT] = __builtin_nontemporal_load(tg + lane + FULL_IT * 64);

        const f32x4* mrow = reinterpret_cast<const f32x4*>(s_mean)   + (size_t)row * (KC * D4);
        const f32x4* lrow = reinterpret_cast<const f32x4*>(s_logstd) + (size_t)row * (KC * D4);

        float a[KC];
        #pragma unroll 1   // keep k rolled: bounds VGPRs, 10 loads in flight per iter
        for (int k = 0; k < KC; ++k) {
            const f32x4* mk = mrow + k * D4;
            const f32x4* lk = lrow + k * D4;

            // Issue ALL loads for this component, grouped by stream.
            f32x4 m[FULL_IT + 1], l[FULL_IT + 1];
            #pragma unroll
            for (int i = 0; i < FULL_IT; ++i)
                m[i] = __builtin_nontemporal_load(mk + lane + i * 64);
            if (lane < REM)
                m[FULL_IT] = __builtin_nontemporal_load(mk + lane + FULL_IT * 64);
            #pragma unroll
            for (int i = 0; i < FULL_IT; ++i)
                l[i] = __builtin_nontemporal_load(lk + lane + i * 64);
            if (lane < REM)
                l[FULL_IT] = __builtin_nontemporal_load(lk + lane + FULL_IT * 64);

            // Dual accumulators break the serial fma chain.
            float z2a = 0.0f, z2b = 0.0f, lsa = 0.0f, lsb = 0.0f;
            #pragma unroll
            for (int i = 0; i < FULL_IT; ++i) {
                float r0 = (t[i].x - m[i].x) * __expf(-l[i].x);
                float r1 = (t[i].y - m[i].y) * __expf(-l[i].y);
                float r2 = (t[i].z - m[i].z) * __expf(-l[i].z);
                float r3 = (t[i].w - m[i].w) * __expf(-l[i].w);
                z2a = fmaf(r0, r0, z2a);  lsa += l[i].x;
                z2b = fmaf(r1, r1, z2b);  lsb += l[i].y;
                z2a = fmaf(r2, r2, z2a);  lsa += l[i].z;
                z2b = fmaf(r3, r3, z2b);  lsb += l[i].w;
            }
            if (lane < REM) {
                float r0 = (t[FULL_IT].x - m[FULL_IT].x) * __expf(-l[FULL_IT].x);
                float r1 = (t[FULL_IT].y - m[FULL_IT].y) * __expf(-l[FULL_IT].y);
                float r2 = (t[FULL_IT].z - m[FULL_IT].z) * __expf(-l[FULL_IT].z);
                float r3 = (t[FULL_IT].w - m[FULL_IT].w) * __expf(-l[FULL_IT].w);
                z2a = fmaf(r0, r0, z2a);  lsa += l[FULL_IT].x;
                z2b = fmaf(r1, r1, z2b);  lsb += l[FULL_IT].y;
                z2a = fmaf(r2, r2, z2a);  lsa += l[FULL_IT].z;
                z2b = fmaf(r3, r3, z2b);  lsb += l[FULL_IT].w;
            }
            // Fold -(0.5*z2 + lsum) BEFORE reducing: one butterfly, not two.
            float c = fmaf(0.5f, z2a + z2b, lsa + lsb);
            #pragma unroll
            for (int off = 32; off; off >>= 1) c += __shfl_xor(c, off);
            a[k] = lm[k] - c;   // log_mix + (-0.5*z2 - lsum)
        }

        // Butterfly left the full sum in every lane: wave-uniform logsumexp,
        // no divergence. Only lane 0's value is consumed below.
        float mx = a[0];
        #pragma unroll
        for (int k = 1; k < KC; ++k) mx = fmaxf(mx, a[k]);
        float s = 0.0f;
        #pragma unroll
        for (int k = 0; k < KC; ++k) s += __expf(a[k] - mx);
        row_loss = -(mx + __logf(s)) * inv_n;
    }

    // Block-level combine: 8 waves -> 1 value per block.
    __shared__ float part[WPB];
    if (lane == 0) part[wave_in_block] = row_loss;
    __syncthreads();
    if (threadIdx.x == 0) {
        float s = 0.0f;
        #pragma unroll
        for (int w = 0; w < WPB; ++w) s += part[w];
        if (use_partials) partials[blockIdx.x] = s;   // plain store, no atomic
        else              atomicAdd(out, s);
    }
}

__global__ __launch_bounds__(256) void reduce_partials_kernel(
    const float* __restrict__ partials, float* __restrict__ out, int n)
{
    float s = 0.0f;
    for (int i = threadIdx.x; i < n; i += 256) s += partials[i];
    #pragma unroll
    for (int off = 32; off; off >>= 1) s += __shfl_xor(s, off);
    __shared__ float part[4];
    if ((threadIdx.x & 63) == 0) part[threadIdx.x >> 6] = s;
    __syncthreads();
    if (threadIdx.x == 0) out[0] = part[0] + part[1] + part[2] + part[3];
}

} // anonymous namespace

extern "C" void kernel_launch(void* const* d_in, const int* in_sizes, int n_in,
                              void* d_out, int out_size, void* d_ws, size_t ws_size,
                              hipStream_t stream)
{
    const float* target   = (const float*)d_in[0];
    const float* s_mean   = (const float*)d_in[1];
    const float* s_logstd = (const float*)d_in[2];
    const float* log_mix  = (const float*)d_in[3];
    float* out = (float*)d_out;

    const int n_rows = in_sizes[0] / DIM;   // 16384
    const int blocks = (n_rows + WPB - 1) / WPB;

    const bool use_partials = (d_ws != nullptr) &&
                              (ws_size >= (size_t)blocks * sizeof(float));

    if (use_partials) {
        // No up-front zero kernel: main kernel starts immediately, partials
        // are plain stores, trailing 1-block reduce overwrites out[0].
        mdn_loss_kernel<<<blocks, 512, 0, stream>>>(
            target, s_mean, s_logstd, log_mix, out, (float*)d_ws,
            n_rows, 1.0f / n_rows, 1);
        reduce_partials_kernel<<<1, 256, 0, stream>>>((const float*)d_ws, out, blocks);
    } else {
        zero_out_kernel<<<1, 1, 0, stream>>>(out);
        mdn_loss_kernel<<<blocks, 512, 0, stream>>>(
            target, s_mean, s_logstd, log_mix, out, nullptr,
            n_rows, 1.0f / n_rows, 0);
    }
}